// Round 20
// baseline (350.487 us; speedup 1.0000x reference)
//
#include <hip/hip_runtime.h>
#include <math.h>
#include <stdint.h>

#define CC 512
#define NN 4096
#define BB 4

typedef _Float16 f16;
typedef _Float16 f16x8 __attribute__((ext_vector_type(8)));
typedef _Float16 f16x4 __attribute__((ext_vector_type(4)));
typedef float f32x4 __attribute__((ext_vector_type(4)));

// ---------- async global->LDS 16B ----------
__device__ __forceinline__ void gload_lds16(const void* g, void* l) {
    __builtin_amdgcn_global_load_lds(
        (const __attribute__((address_space(1))) void*)g,
        (__attribute__((address_space(3))) void*)l, 16, 0, 0);
}

// Stage ROWS rows x 64 f16 from K-major global into linear LDS; source pre-swizzled.
template<int ROWS>
__device__ __forceinline__ void stage_tile(const f16* __restrict__ g, int stride_e,
                                           f16* lds, int wid, int lane) {
    constexpr int ITERS = ROWS * 8 / 64 / 4;   // 4 waves
    #pragma unroll
    for (int it = 0; it < ITERS; ++it) {
        int flatbase = (wid * ITERS + it) * 64;
        f16* dst = lds + flatbase * 8;
        int flat = flatbase + lane;
        int r = flat >> 3, c = flat & 7;
        const f16* src = g + (size_t)r * stride_e + ((c ^ (r & 7)) << 3);
        gload_lds16(src, dst);
    }
}

__device__ __forceinline__ f16x8 frag_ld(const f16* lds, int r, int ch) {
    return *(const f16x8*)(lds + r * 64 + ((ch ^ (r & 7)) << 3));
}

#define MFMA16(a, b, c) __builtin_amdgcn_mfma_f32_16x16x32_f16((a), (b), (c), 0, 0, 0)

// ---------- DPP row_ror reductions over 16-lane rows (VALU only) ----------
template<int N>
__device__ __forceinline__ float ror16(float x) {
    return __int_as_float(__builtin_amdgcn_update_dpp(
        0, __float_as_int(x), 0x120 + N, 0xF, 0xF, true));
}
__device__ __forceinline__ f32x4 rmax16(f32x4 v) {
    #pragma unroll
    for (int q = 0; q < 4; ++q) {
        float x = v[q];
        x = fmaxf(x, ror16<1>(x));
        x = fmaxf(x, ror16<2>(x));
        x = fmaxf(x, ror16<4>(x));
        x = fmaxf(x, ror16<8>(x));
        v[q] = x;
    }
    return v;
}
__device__ __forceinline__ f32x4 rsum16(f32x4 v) {
    #pragma unroll
    for (int q = 0; q < 4; ++q) {
        float x = v[q];
        x += ror16<1>(x);
        x += ror16<2>(x);
        x += ror16<4>(x);
        x += ror16<8>(x);
        v[q] = x;
    }
    return v;
}

// ---------------- W conversion ----------------
__global__ __launch_bounds__(256) void wcvt_k(const float* __restrict__ Wb,
                                              const float* __restrict__ Wc,
                                              const float* __restrict__ Wd,
                                              f16* __restrict__ W16) {
    int i = blockIdx.x * 256 + threadIdx.x;
    int idx = i * 4;
    int m = idx >> 18;
    int off = idx & 262143;
    const float* src = (m == 0) ? Wb : (m == 1) ? Wc : Wd;
    f32x4 v = *(const f32x4*)(src + off);
    f16x4 h = { (f16)v[0], (f16)v[1], (f16)v[2], (f16)v[3] };
    *(f16x4*)(W16 + idx) = h;
}

// ---------------- x transpose-convert: Xt[b][n][c] f16 = x[b][c][n] ----------------
__global__ __launch_bounds__(256) void xt_k(const float* __restrict__ x,
                                            f16* __restrict__ Xt) {
    const int b = blockIdx.z;
    const int c0 = blockIdx.y * 64, n0 = blockIdx.x * 64;
    __shared__ float T[64][65];
    const int t = threadIdx.x;
    const float* __restrict__ xb = x + (size_t)b * CC * NN;
    const int cl = t >> 4, n4 = (t & 15) * 4;
    #pragma unroll
    for (int it = 0; it < 4; ++it) {
        f32x4 v = *(const f32x4*)(xb + (size_t)(c0 + cl + it * 16) * NN + n0 + n4);
        T[cl + it * 16][n4 + 0] = v[0];
        T[cl + it * 16][n4 + 1] = v[1];
        T[cl + it * 16][n4 + 2] = v[2];
        T[cl + it * 16][n4 + 3] = v[3];
    }
    __syncthreads();
    f16* __restrict__ xtb = Xt + (size_t)b * NN * CC;
    const int nl = t >> 2, seg = (t & 3) * 16;
    f16 tmp[16];
    #pragma unroll
    for (int j = 0; j < 16; ++j) tmp[j] = (f16)T[seg + j][nl];
    *(f16x8*)(xtb + (size_t)(n0 + nl) * CC + c0 + seg)     = *(f16x8*)(tmp);
    *(f16x8*)(xtb + (size_t)(n0 + nl) * CC + c0 + seg + 8) = *(f16x8*)(tmp + 8);
}

// ---------------- proj (all batches): O = W @ x, both operands f16 K-major ----------------
// Bt (wsel==0) is pre-scaled by log2(e): flash runs softmax in exp2 domain
// (v_exp_f32 is natively 2^x; saves one v_mul per exp on the producer hot path).
__global__ __launch_bounds__(256) void proj_k(const f16* __restrict__ Xt,
                                              const f16* __restrict__ W16,
                                              f16* __restrict__ Bt, f16* __restrict__ Ct,
                                              f16* __restrict__ Dm) {
    const int wsel = blockIdx.z % 3;
    const int b = blockIdx.z / 3;
    const f16* __restrict__ W = W16 + (size_t)wsel * CC * CC;
    const f16* __restrict__ XtB = Xt + (size_t)b * NN * CC;   // [n][c]
    const size_t p16 = (size_t)CC * NN;
    const int o0 = blockIdx.y * 128, n0 = blockIdx.x * 128;

    __shared__ __align__(16) char smraw[34816];
    f16* As = (f16*)smraw;
    f16* Bs = As + 128 * 64;
    f16* T  = (f16*)smraw;

    const int t = threadIdx.x;
    const int wid = t >> 6, lane = t & 63;
    const int wr = wid >> 1, wc = wid & 1;

    f32x4 acc[4][4] = {};

    for (int kc = 0; kc < CC; kc += 64) {
        __syncthreads();
        stage_tile<128>(W + (size_t)o0 * CC + kc, CC, As, wid, lane);
        stage_tile<128>(XtB + (size_t)n0 * CC + kc, CC, Bs, wid, lane);
        __syncthreads();
        #pragma unroll
        for (int ks = 0; ks < 2; ++ks) {
            int ch = ks * 4 + (lane >> 4);
            f16x8 a[4], bb[4];
            #pragma unroll
            for (int i = 0; i < 4; ++i) a[i]  = frag_ld(As, wr * 64 + i * 16 + (lane & 15), ch);
            #pragma unroll
            for (int j = 0; j < 4; ++j) bb[j] = frag_ld(Bs, wc * 64 + j * 16 + (lane & 15), ch);
            #pragma unroll
            for (int i = 0; i < 4; ++i)
                #pragma unroll
                for (int j = 0; j < 4; ++j)
                    acc[i][j] = MFMA16(a[i], bb[j], acc[i][j]);
        }
    }

    __syncthreads();
    const float osc = (wsel == 0) ? 1.4426950408889634f : 1.0f;   // log2(e) for Bt only
    if (wsel < 2) {
        #pragma unroll
        for (int i = 0; i < 4; ++i)
            #pragma unroll
            for (int j = 0; j < 4; ++j) {
                int n_l = wc * 64 + j * 16 + (lane & 15);
                int o_l = wr * 64 + i * 16 + (lane >> 4) * 4;
                f16x4 h = { (f16)(acc[i][j][0] * osc), (f16)(acc[i][j][1] * osc),
                            (f16)(acc[i][j][2] * osc), (f16)(acc[i][j][3] * osc) };
                *(f16x4*)(T + n_l * 136 + o_l) = h;
            }
        __syncthreads();
        f16* __restrict__ dst = ((wsel == 0) ? Bt : Ct) + (size_t)b * p16;
        int n = t & 127;
        #pragma unroll
        for (int it = 0; it < 8; ++it) {
            int ch8 = (t >> 7) * 8 + it;
            f16x8 h = *(f16x8*)(T + n * 136 + ch8 * 8);
            *(f16x8*)(dst + (size_t)(n0 + n) * CC + o0 + ch8 * 8) = h;
        }
    } else {
        #pragma unroll
        for (int i = 0; i < 4; ++i)
            #pragma unroll
            for (int j = 0; j < 4; ++j) {
                int n_l = wc * 64 + j * 16 + (lane & 15);
                #pragma unroll
                for (int q = 0; q < 4; ++q) {
                    int o_l = wr * 64 + i * 16 + (lane >> 4) * 4 + q;
                    T[o_l * 136 + n_l] = (f16)acc[i][j][q];
                }
            }
        __syncthreads();
        f16* __restrict__ dst = Dm + (size_t)b * p16;
        int o = t & 127;
        #pragma unroll
        for (int it = 0; it < 8; ++it) {
            int ch8 = (t >> 7) * 8 + it;
            f16x8 h = *(f16x8*)(T + o * 136 + ch8 * 8);
            *(f16x8*)(dst + (size_t)(o0 + o) * NN + n0 + ch8 * 8) = h;
        }
    }
}

// ---------- flash staging (32-m tiles) ----------
__device__ __forceinline__ void stage_Ct32(const f16* __restrict__ Ctb, f16* dstbase,
                                           int m0, int w4, int lane) {
    #pragma unroll
    for (int it = 0; it < 8; ++it) {
        int flatbase = (w4 * 8 + it) * 64;
        f16* dst = dstbase + flatbase * 8;
        int r = flatbase >> 6;                // uniform: w4*8+it
        const f16* src = Ctb + (size_t)(m0 + r) * CC + ((lane ^ (r & 7)) << 3);
        gload_lds16(src, dst);
    }
}
// DtB tile [512 c][32 m], rows 64B apart, both-sides quarter swizzle (r19, proven).
__device__ __forceinline__ void stage_Dt32(const f16* __restrict__ Dmb, f16* DtB,
                                           int m0, int w4, int lane) {
    #pragma unroll
    for (int it = 0; it < 8; ++it) {
        int flatbase = (w4 * 8 + it) * 64;
        f16* dst = DtB + flatbase * 8;
        int flat = flatbase + lane;
        int r = flat >> 2, c4 = flat & 3;
        const f16* src = Dmb + (size_t)r * NN + m0 + (((c4 ^ ((r >> 1) & 3))) << 3);
        gload_lds16(src, dst);
    }
}

#define PSTRIDE 40
#define PBUF    2560   // 64 * PSTRIDE
#define THR2    11.5415603f   // 8 nats in bits

// ---------------- fused flash attention: r19 + 4-chain QK + exp2 softmax ----------------
// Proven base (r19: 298.6us flash, zero spill). Waves 0-3: QK^T + wave-local softmax
// (T13 defer-rescale, exp2 domain — Bt pre-scaled by log2e in proj). Waves 4-7:
// PV(i-1), O = 64n x 128c; restage Dt after PV. ONE __syncthreads per iter.
// QK now uses 4 accumulator chains (a/b K-halves) to halve MFMA dependency depth.
__global__ __launch_bounds__(512) void flash_k(
    const float* __restrict__ x, const float* __restrict__ gamma_p,
    const f16* __restrict__ Bt, const f16* __restrict__ Ct,
    const f16* __restrict__ Dm, float* __restrict__ out)
{
    __shared__ __align__(16) char sm[139776];
    f16*   CtB  = (f16*)sm;                    // [2][32][512]  65536 B
    f16*   DtB  = (f16*)(sm + 65536);          // [512][32]     32768 B (quarter-swizzled)
    f16*   PSB  = (f16*)(sm + 98304);          // [2][64][40]   10240 B (padded stride)
    float* SCL  = (float*)(sm + 108544);       // [2][64]         512 B
    int*   FLG  = (int*)(sm + 109056);         // [2][4]           32 B
    float* LROW = (float*)(sm + 139264);       // [64]            256 B (beyond T)
    // epilogue: T = (float*)sm, [512][68] f32 = 139264 B

    // XCD-pair swizzle: 256 blocks
    const int bx = blockIdx.x;
    const int j8 = bx & 7;
    const int b = j8 >> 1;
    const int n0 = ((bx >> 3) + (j8 & 1) * 32) * 64;

    const size_t p16 = (size_t)CC * NN;
    const f16* __restrict__ Btb = Bt + (size_t)b * p16;   // [n][c] (log2e-scaled)
    const f16* __restrict__ Ctb = Ct + (size_t)b * p16;   // [m][c]
    const f16* __restrict__ Dmb = Dm + (size_t)b * p16;   // [c][m]

    const int t = threadIdx.x;
    const int wid = t >> 6, lane = t & 63;
    const int w4 = wid & 3;
    const bool isP = wid < 4;                  // producer gang
    const int l15 = lane & 15, g = lane >> 4;
    // Dt read-quarter swizzle (r19)
    const int dq = (g ^ ((l15 >> 1) & 3)) << 3;

    f32x4 R[32];                               // producer: R[0..15] = Q; consumer: O[4][8]
    f32x4 m_run = (f32x4)(-INFINITY);
    f32x4 l_run = (f32x4)(0.f);

    if (isP) {
        const f16* qrow = Btb + (size_t)(n0 + w4 * 16 + l15) * CC + g * 8;
        #pragma unroll
        for (int s = 0; s < 16; ++s)
            R[s] = __builtin_bit_cast(f32x4, *(const f16x8*)(qrow + s * 32));
    } else {
        #pragma unroll
        for (int i = 0; i < 32; ++i) R[i] = (f32x4)(0.f);
    }

    if (isP) stage_Ct32(Ctb, CtB, 0, w4, lane);
    __syncthreads();

    for (int i = 0; i < 128; ++i) {
        const int cur = i & 1;
        if (isP) {
            // prefetch Ct(i+1) into other buffer (lands during this iter)
            if (i + 1 < 128) stage_Ct32(Ctb, CtB + (cur ^ 1) * 16384, (i + 1) * 32, w4, lane);
            // ---- QK(i): 16n x 32m per wave; 4 accumulator chains (depth 8) ----
            f32x4 S0a = (f32x4)(0.f), S1a = (f32x4)(0.f);
            f32x4 S0b = (f32x4)(0.f), S1b = (f32x4)(0.f);
            const f16* cb = CtB + cur * 16384;
            __builtin_amdgcn_s_setprio(1);
            #pragma unroll
            for (int s = 0; s < 8; ++s) {
                int ch0 = s * 4 + g;
                int ch1 = (s + 8) * 4 + g;
                f16x8 b00 = *(const f16x8*)(cb + l15 * 512 + ((ch0 ^ (l15 & 7)) << 3));
                f16x8 b01 = *(const f16x8*)(cb + (16 + l15) * 512 + ((ch0 ^ (l15 & 7)) << 3));
                f16x8 b10 = *(const f16x8*)(cb + l15 * 512 + ((ch1 ^ (l15 & 7)) << 3));
                f16x8 b11 = *(const f16x8*)(cb + (16 + l15) * 512 + ((ch1 ^ (l15 & 7)) << 3));
                f16x8 qa = __builtin_bit_cast(f16x8, R[s]);
                f16x8 qb = __builtin_bit_cast(f16x8, R[s + 8]);
                S0a = MFMA16(qa, b00, S0a);
                S1a = MFMA16(qa, b01, S1a);
                S0b = MFMA16(qb, b10, S0b);
                S1b = MFMA16(qb, b11, S1b);
            }
            __builtin_amdgcn_s_setprio(0);
            f32x4 S0, S1;
            #pragma unroll
            for (int q = 0; q < 4; ++q) { S0[q] = S0a[q] + S0b[q]; S1[q] = S1a[q] + S1b[q]; }
            // ---- wave-local softmax (exp2 domain) with T13 defer-rescale ----
            f32x4 tm, scl;
            #pragma unroll
            for (int q = 0; q < 4; ++q) tm[q] = fmaxf(S0[q], S1[q]);
            tm = rmax16(tm);
            int grow = 0;
            #pragma unroll
            for (int q = 0; q < 4; ++q) grow |= (tm[q] > m_run[q] + THR2) ? 1 : 0;
            const bool doR = __any(grow);
            if (doR) {
                #pragma unroll
                for (int q = 0; q < 4; ++q) {
                    float mnew = fmaxf(m_run[q], tm[q]);
                    scl[q] = exp2f(m_run[q] - mnew);
                    m_run[q] = mnew;
                }
            } else {
                #pragma unroll
                for (int q = 0; q < 4; ++q) scl[q] = 1.0f;
            }
            #pragma unroll
            for (int q = 0; q < 4; ++q) {
                S0[q] = exp2f(S0[q] - m_run[q]);
                S1[q] = exp2f(S1[q] - m_run[q]);
            }
            f32x4 ps;
            #pragma unroll
            for (int q = 0; q < 4; ++q) ps[q] = S0[q] + S1[q];
            ps = rsum16(ps);
            #pragma unroll
            for (int q = 0; q < 4; ++q) l_run[q] = l_run[q] * scl[q] + ps[q];
            if (l15 == 0) *(f32x4*)(SCL + cur * 64 + w4 * 16 + g * 4) = scl;
            if (lane == 0) FLG[cur * 4 + w4] = doR ? 1 : 0;
            // P write, chunk-swizzled, padded stride
            f16* pp = PSB + cur * PBUF;
            #pragma unroll
            for (int q = 0; q < 4; ++q) {
                int row = w4 * 16 + g * 4 + q;
                pp[row * PSTRIDE + ((((l15 >> 3) ^ g) << 3) | (l15 & 7))] = (f16)S0[q];
                pp[row * PSTRIDE + ((((2 + (l15 >> 3)) ^ g) << 3) | (l15 & 7))] = (f16)S1[q];
            }
        } else {
            if (i > 0) {
                // ---- PV(i-1): 64n x 128c per wave ----
                const int prev = cur ^ 1;
                const f16* pp = PSB + prev * PBUF;
                const int fl = FLG[prev * 4 + 0] | FLG[prev * 4 + 1] |
                               FLG[prev * 4 + 2] | FLG[prev * 4 + 3];
                if (fl) {                      // wave-uniform branch
                    const float* sc = SCL + prev * 64;
                    f32x4 scl4[4];
                    #pragma unroll
                    for (int na = 0; na < 4; ++na)
                        scl4[na] = *(const f32x4*)(sc + na * 16 + g * 4);
                    #pragma unroll
                    for (int na = 0; na < 4; ++na)
                        #pragma unroll
                        for (int cb = 0; cb < 8; ++cb)
                            #pragma unroll
                            for (int q = 0; q < 4; ++q)
                                R[na * 8 + cb][q] *= scl4[na][q];
                }
                f16x8 pa[4];
                #pragma unroll
                for (int na = 0; na < 4; ++na) {
                    int row = na * 16 + l15;
                    pa[na] = *(const f16x8*)(pp + row * PSTRIDE + ((g ^ (l15 >> 2)) << 3));
                }
                f16x8 d[8];
                #pragma unroll
                for (int cb = 0; cb < 8; ++cb)
                    d[cb] = *(const f16x8*)(DtB + (w4 * 128 + cb * 16 + l15) * 32 + dq);
                __builtin_amdgcn_s_setprio(1);
                #pragma unroll
                for (int na = 0; na < 4; ++na)
                    #pragma unroll
                    for (int cb = 0; cb < 8; ++cb)
                        R[na * 8 + cb] = MFMA16(pa[na], d[cb], R[na * 8 + cb]);
                __builtin_amdgcn_s_setprio(0);
                __builtin_amdgcn_sched_barrier(0);   // keep Dt restage below the reads
            }
            // restage own rows with Dt(i) (consumed at iter i+1)
            stage_Dt32(Dmb, DtB, i * 32, w4, lane);
        }
        __syncthreads();
    }

    // ---- epilogue E1: consumer does PV(127); producer publishes l ----
    if (isP) {
        if (l15 == 0) *(f32x4*)(LROW + w4 * 16 + g * 4) = l_run;
    } else {
        const f16* pp = PSB + PBUF;            // prev = 127&1 = 1
        const int fl = FLG[4 + 0] | FLG[4 + 1] | FLG[4 + 2] | FLG[4 + 3];
        if (fl) {
            const float* sc = SCL + 64;
            f32x4 scl4[4];
            #pragma unroll
            for (int na = 0; na < 4; ++na)
                scl4[na] = *(const f32x4*)(sc + na * 16 + g * 4);
            #pragma unroll
            for (int na = 0; na < 4; ++na)
                #pragma unroll
                for (int cb = 0; cb < 8; ++cb)
                    #pragma unroll
                    for (int q = 0; q < 4; ++q)
                        R[na * 8 + cb][q] *= scl4[na][q];
        }
        f16x8 pa[4];
        #pragma unroll
        for (int na = 0; na < 4; ++na) {
            int row = na * 16 + l15;
            pa[na] = *(const f16x8*)(pp + row * PSTRIDE + ((g ^ (l15 >> 2)) << 3));
        }
        f16x8 d[8];
        #pragma unroll
        for (int cb = 0; cb < 8; ++cb)
            d[cb] = *(const f16x8*)(DtB + (w4 * 128 + cb * 16 + l15) * 32 + dq);
        #pragma unroll
        for (int na = 0; na < 4; ++na)
            #pragma unroll
            for (int cb = 0; cb < 8; ++cb)
                R[na * 8 + cb] = MFMA16(pa[na], d[cb], R[na * 8 + cb]);
    }
    __syncthreads();

    // ---- E2: consumer writes T[c][n] = gamma * O / l ----
    const float gam = gamma_p[0];
    float* T = (float*)sm;                     // [512][68] f32 (LROW lives beyond)
    if (!isP) {
        #pragma unroll
        for (int na = 0; na < 4; ++na) {
            f32x4 lr = *(const f32x4*)(LROW + na * 16 + g * 4);
            f32x4 inv;
            #pragma unroll
            for (int q = 0; q < 4; ++q) inv[q] = gam / lr[q];
            #pragma unroll
            for (int cb = 0; cb < 8; ++cb) {
                int c = w4 * 128 + cb * 16 + l15;
                f32x4 v;
                #pragma unroll
                for (int q = 0; q < 4; ++q) v[q] = R[na * 8 + cb][q] * inv[q];
                *(f32x4*)(T + c * 68 + na * 16 + g * 4) = v;
            }
        }
    }
    __syncthreads();

    // ---- E3: all threads: out[c][n] = T + x ----
    const float* __restrict__ xb = x + (size_t)b * CC * NN;
    float* __restrict__ ob = out + (size_t)b * CC * NN;
    #pragma unroll
    for (int it = 0; it < 16; ++it) {
        int c = (t >> 4) + it * 32;
        int n4 = (t & 15) * 4;
        f32x4 v = *(const f32x4*)(T + c * 68 + n4);
        f32x4 xv = *(const f32x4*)(xb + (size_t)c * NN + n0 + n4);
        #pragma unroll
        for (int q = 0; q < 4; ++q) v[q] += xv[q];
        *(f32x4*)(ob + (size_t)c * NN + n0 + n4) = v;
    }
}

extern "C" void kernel_launch(void* const* d_in, const int* in_sizes, int n_in,
                              void* d_out, int out_size, void* d_ws, size_t ws_size,
                              hipStream_t stream) {
    const float* x  = (const float*)d_in[0];
    const float* Wb = (const float*)d_in[1];
    const float* Wc = (const float*)d_in[2];
    const float* Wd = (const float*)d_in[3];
    const float* gm = (const float*)d_in[4];
    float* out = (float*)d_out;
    char* ws = (char*)d_ws;

    // ws: W16 1.5MB | Bt 16MB | Ct 16MB | Dm 16MB | Xt 16MB  (~66MB)
    f16* W16 = (f16*)(ws);
    f16* Bt  = (f16*)(ws + 1572864);
    f16* Ct  = (f16*)(ws + 1572864 + 16777216);
    f16* Dm  = (f16*)(ws + 1572864 + 2 * 16777216);
    f16* Xt  = (f16*)(ws + 1572864 + 3 * 16777216);

    wcvt_k<<<dim3(768), 256, 0, stream>>>(Wb, Wc, Wd, W16);
    xt_k<<<dim3(NN / 64, CC / 64, BB), 256, 0, stream>>>(x, Xt);
    proj_k<<<dim3(32, 4, 12), 256, 0, stream>>>(Xt, W16, Bt, Ct, Dm);
    flash_k<<<dim3(256), 512, 0, stream>>>(x, gm, Bt, Ct, Dm, out);
}

// Round 21
// 330.224 us; speedup vs baseline: 1.0614x; 1.0614x over previous
//
#include <hip/hip_runtime.h>
#include <math.h>
#include <stdint.h>

#define CC 512
#define NN 4096
#define BB 4

typedef _Float16 f16;
typedef _Float16 f16x8 __attribute__((ext_vector_type(8)));
typedef _Float16 f16x4 __attribute__((ext_vector_type(4)));
typedef float f32x4 __attribute__((ext_vector_type(4)));

// ---------- async global->LDS 16B ----------
__device__ __forceinline__ void gload_lds16(const void* g, void* l) {
    __builtin_amdgcn_global_load_lds(
        (const __attribute__((address_space(1))) void*)g,
        (__attribute__((address_space(3))) void*)l, 16, 0, 0);
}

// Stage ROWS rows x 64 f16 from K-major global into linear LDS; source pre-swizzled.
template<int ROWS>
__device__ __forceinline__ void stage_tile(const f16* __restrict__ g, int stride_e,
                                           f16* lds, int wid, int lane) {
    constexpr int ITERS = ROWS * 8 / 64 / 4;   // 4 waves
    #pragma unroll
    for (int it = 0; it < ITERS; ++it) {
        int flatbase = (wid * ITERS + it) * 64;
        f16* dst = lds + flatbase * 8;
        int flat = flatbase + lane;
        int r = flat >> 3, c = flat & 7;
        const f16* src = g + (size_t)r * stride_e + ((c ^ (r & 7)) << 3);
        gload_lds16(src, dst);
    }
}

__device__ __forceinline__ f16x8 frag_ld(const f16* lds, int r, int ch) {
    return *(const f16x8*)(lds + r * 64 + ((ch ^ (r & 7)) << 3));
}

#define MFMA16(a, b, c) __builtin_amdgcn_mfma_f32_16x16x32_f16((a), (b), (c), 0, 0, 0)

// ---------- DPP row_ror reductions over 16-lane rows (VALU only) ----------
template<int N>
__device__ __forceinline__ float ror16(float x) {
    return __int_as_float(__builtin_amdgcn_update_dpp(
        0, __float_as_int(x), 0x120 + N, 0xF, 0xF, true));
}
__device__ __forceinline__ f32x4 rmax16(f32x4 v) {
    #pragma unroll
    for (int q = 0; q < 4; ++q) {
        float x = v[q];
        x = fmaxf(x, ror16<1>(x));
        x = fmaxf(x, ror16<2>(x));
        x = fmaxf(x, ror16<4>(x));
        x = fmaxf(x, ror16<8>(x));
        v[q] = x;
    }
    return v;
}
__device__ __forceinline__ f32x4 rsum16(f32x4 v) {
    #pragma unroll
    for (int q = 0; q < 4; ++q) {
        float x = v[q];
        x += ror16<1>(x);
        x += ror16<2>(x);
        x += ror16<4>(x);
        x += ror16<8>(x);
        v[q] = x;
    }
    return v;
}

// ---------------- W conversion ----------------
__global__ __launch_bounds__(256) void wcvt_k(const float* __restrict__ Wb,
                                              const float* __restrict__ Wc,
                                              const float* __restrict__ Wd,
                                              f16* __restrict__ W16) {
    int i = blockIdx.x * 256 + threadIdx.x;
    int idx = i * 4;
    int m = idx >> 18;
    int off = idx & 262143;
    const float* src = (m == 0) ? Wb : (m == 1) ? Wc : Wd;
    f32x4 v = *(const f32x4*)(src + off);
    f16x4 h = { (f16)v[0], (f16)v[1], (f16)v[2], (f16)v[3] };
    *(f16x4*)(W16 + idx) = h;
}

// ---------------- x transpose-convert: Xt[b][n][c] f16 = x[b][c][n] ----------------
__global__ __launch_bounds__(256) void xt_k(const float* __restrict__ x,
                                            f16* __restrict__ Xt) {
    const int b = blockIdx.z;
    const int c0 = blockIdx.y * 64, n0 = blockIdx.x * 64;
    __shared__ float T[64][65];
    const int t = threadIdx.x;
    const float* __restrict__ xb = x + (size_t)b * CC * NN;
    const int cl = t >> 4, n4 = (t & 15) * 4;
    #pragma unroll
    for (int it = 0; it < 4; ++it) {
        f32x4 v = *(const f32x4*)(xb + (size_t)(c0 + cl + it * 16) * NN + n0 + n4);
        T[cl + it * 16][n4 + 0] = v[0];
        T[cl + it * 16][n4 + 1] = v[1];
        T[cl + it * 16][n4 + 2] = v[2];
        T[cl + it * 16][n4 + 3] = v[3];
    }
    __syncthreads();
    f16* __restrict__ xtb = Xt + (size_t)b * NN * CC;
    const int nl = t >> 2, seg = (t & 3) * 16;
    f16 tmp[16];
    #pragma unroll
    for (int j = 0; j < 16; ++j) tmp[j] = (f16)T[seg + j][nl];
    *(f16x8*)(xtb + (size_t)(n0 + nl) * CC + c0 + seg)     = *(f16x8*)(tmp);
    *(f16x8*)(xtb + (size_t)(n0 + nl) * CC + c0 + seg + 8) = *(f16x8*)(tmp + 8);
}

// ---------------- proj (all batches): O = W @ x, both operands f16 K-major ----------------
// Bt (wsel==0) is pre-scaled by log2(e): flash runs softmax in exp2 domain
// (v_exp_f32 is natively 2^x; saves one v_mul per exp on the producer hot path).
__global__ __launch_bounds__(256) void proj_k(const f16* __restrict__ Xt,
                                              const f16* __restrict__ W16,
                                              f16* __restrict__ Bt, f16* __restrict__ Ct,
                                              f16* __restrict__ Dm) {
    const int wsel = blockIdx.z % 3;
    const int b = blockIdx.z / 3;
    const f16* __restrict__ W = W16 + (size_t)wsel * CC * CC;
    const f16* __restrict__ XtB = Xt + (size_t)b * NN * CC;   // [n][c]
    const size_t p16 = (size_t)CC * NN;
    const int o0 = blockIdx.y * 128, n0 = blockIdx.x * 128;

    __shared__ __align__(16) char smraw[34816];
    f16* As = (f16*)smraw;
    f16* Bs = As + 128 * 64;
    f16* T  = (f16*)smraw;

    const int t = threadIdx.x;
    const int wid = t >> 6, lane = t & 63;
    const int wr = wid >> 1, wc = wid & 1;

    f32x4 acc[4][4] = {};

    for (int kc = 0; kc < CC; kc += 64) {
        __syncthreads();
        stage_tile<128>(W + (size_t)o0 * CC + kc, CC, As, wid, lane);
        stage_tile<128>(XtB + (size_t)n0 * CC + kc, CC, Bs, wid, lane);
        __syncthreads();
        #pragma unroll
        for (int ks = 0; ks < 2; ++ks) {
            int ch = ks * 4 + (lane >> 4);
            f16x8 a[4], bb[4];
            #pragma unroll
            for (int i = 0; i < 4; ++i) a[i]  = frag_ld(As, wr * 64 + i * 16 + (lane & 15), ch);
            #pragma unroll
            for (int j = 0; j < 4; ++j) bb[j] = frag_ld(Bs, wc * 64 + j * 16 + (lane & 15), ch);
            #pragma unroll
            for (int i = 0; i < 4; ++i)
                #pragma unroll
                for (int j = 0; j < 4; ++j)
                    acc[i][j] = MFMA16(a[i], bb[j], acc[i][j]);
        }
    }

    __syncthreads();
    const float osc = (wsel == 0) ? 1.4426950408889634f : 1.0f;   // log2(e) for Bt only
    if (wsel < 2) {
        #pragma unroll
        for (int i = 0; i < 4; ++i)
            #pragma unroll
            for (int j = 0; j < 4; ++j) {
                int n_l = wc * 64 + j * 16 + (lane & 15);
                int o_l = wr * 64 + i * 16 + (lane >> 4) * 4;
                f16x4 h = { (f16)(acc[i][j][0] * osc), (f16)(acc[i][j][1] * osc),
                            (f16)(acc[i][j][2] * osc), (f16)(acc[i][j][3] * osc) };
                *(f16x4*)(T + n_l * 136 + o_l) = h;
            }
        __syncthreads();
        f16* __restrict__ dst = ((wsel == 0) ? Bt : Ct) + (size_t)b * p16;
        int n = t & 127;
        #pragma unroll
        for (int it = 0; it < 8; ++it) {
            int ch8 = (t >> 7) * 8 + it;
            f16x8 h = *(f16x8*)(T + n * 136 + ch8 * 8);
            *(f16x8*)(dst + (size_t)(n0 + n) * CC + o0 + ch8 * 8) = h;
        }
    } else {
        #pragma unroll
        for (int i = 0; i < 4; ++i)
            #pragma unroll
            for (int j = 0; j < 4; ++j) {
                int n_l = wc * 64 + j * 16 + (lane & 15);
                #pragma unroll
                for (int q = 0; q < 4; ++q) {
                    int o_l = wr * 64 + i * 16 + (lane >> 4) * 4 + q;
                    T[o_l * 136 + n_l] = (f16)acc[i][j][q];
                }
            }
        __syncthreads();
        f16* __restrict__ dst = Dm + (size_t)b * p16;
        int o = t & 127;
        #pragma unroll
        for (int it = 0; it < 8; ++it) {
            int ch8 = (t >> 7) * 8 + it;
            f16x8 h = *(f16x8*)(T + o * 136 + ch8 * 8);
            *(f16x8*)(dst + (size_t)(o0 + o) * NN + n0 + ch8 * 8) = h;
        }
    }
}

// ---------- flash staging (32-m tiles) ----------
__device__ __forceinline__ void stage_Ct32(const f16* __restrict__ Ctb, f16* dstbase,
                                           int m0, int w4, int lane) {
    #pragma unroll
    for (int it = 0; it < 8; ++it) {
        int flatbase = (w4 * 8 + it) * 64;
        f16* dst = dstbase + flatbase * 8;
        int r = flatbase >> 6;                // uniform: w4*8+it
        const f16* src = Ctb + (size_t)(m0 + r) * CC + ((lane ^ (r & 7)) << 3);
        gload_lds16(src, dst);
    }
}
// DtB tile [512 c][32 m], rows 64B apart, both-sides quarter swizzle (r19, proven).
__device__ __forceinline__ void stage_Dt32(const f16* __restrict__ Dmb, f16* DtB,
                                           int m0, int w4, int lane) {
    #pragma unroll
    for (int it = 0; it < 8; ++it) {
        int flatbase = (w4 * 8 + it) * 64;
        f16* dst = DtB + flatbase * 8;
        int flat = flatbase + lane;
        int r = flat >> 2, c4 = flat & 3;
        const f16* src = Dmb + (size_t)r * NN + m0 + (((c4 ^ ((r >> 1) & 3))) << 3);
        gload_lds16(src, dst);
    }
}

#define PSTRIDE 40
#define PBUF    2560   // 64 * PSTRIDE
#define THR2    11.5415603f   // 8 nats in bits

// ---------------- fused flash attention: r19 structure + exp2 softmax ONLY ----------------
// r19 proven base (298.6us flash, zero spill): waves 0-3 QK^T (2-chain, depth 16) +
// wave-local softmax + T13 defer-rescale; waves 4-7 PV(i-1), restage Dt after PV;
// ONE __syncthreads per iter; Dt both-sides quarter swizzle; padded P stride.
// ONE change vs r19: softmax in exp2 domain (Bt log2e-scaled at proj; exp2f + THR in
// bits) — removes ~12 v_mul/iter/producer. r20's 4-chain QK split REVERTED (it raised
// VALUBusy 27.8->29.4 and cost 11us).
__global__ __launch_bounds__(512) void flash_k(
    const float* __restrict__ x, const float* __restrict__ gamma_p,
    const f16* __restrict__ Bt, const f16* __restrict__ Ct,
    const f16* __restrict__ Dm, float* __restrict__ out)
{
    __shared__ __align__(16) char sm[139776];
    f16*   CtB  = (f16*)sm;                    // [2][32][512]  65536 B
    f16*   DtB  = (f16*)(sm + 65536);          // [512][32]     32768 B (quarter-swizzled)
    f16*   PSB  = (f16*)(sm + 98304);          // [2][64][40]   10240 B (padded stride)
    float* SCL  = (float*)(sm + 108544);       // [2][64]         512 B
    int*   FLG  = (int*)(sm + 109056);         // [2][4]           32 B
    float* LROW = (float*)(sm + 139264);       // [64]            256 B (beyond T)
    // epilogue: T = (float*)sm, [512][68] f32 = 139264 B

    // XCD-pair swizzle: 256 blocks
    const int bx = blockIdx.x;
    const int j8 = bx & 7;
    const int b = j8 >> 1;
    const int n0 = ((bx >> 3) + (j8 & 1) * 32) * 64;

    const size_t p16 = (size_t)CC * NN;
    const f16* __restrict__ Btb = Bt + (size_t)b * p16;   // [n][c] (log2e-scaled)
    const f16* __restrict__ Ctb = Ct + (size_t)b * p16;   // [m][c]
    const f16* __restrict__ Dmb = Dm + (size_t)b * p16;   // [c][m]

    const int t = threadIdx.x;
    const int wid = t >> 6, lane = t & 63;
    const int w4 = wid & 3;
    const bool isP = wid < 4;                  // producer gang
    const int l15 = lane & 15, g = lane >> 4;
    // Dt read-quarter swizzle (r19)
    const int dq = (g ^ ((l15 >> 1) & 3)) << 3;

    f32x4 R[32];                               // producer: R[0..15] = Q; consumer: O[4][8]
    f32x4 m_run = (f32x4)(-INFINITY);
    f32x4 l_run = (f32x4)(0.f);

    if (isP) {
        const f16* qrow = Btb + (size_t)(n0 + w4 * 16 + l15) * CC + g * 8;
        #pragma unroll
        for (int s = 0; s < 16; ++s)
            R[s] = __builtin_bit_cast(f32x4, *(const f16x8*)(qrow + s * 32));
    } else {
        #pragma unroll
        for (int i = 0; i < 32; ++i) R[i] = (f32x4)(0.f);
    }

    if (isP) stage_Ct32(Ctb, CtB, 0, w4, lane);
    __syncthreads();

    for (int i = 0; i < 128; ++i) {
        const int cur = i & 1;
        if (isP) {
            // prefetch Ct(i+1) into other buffer (lands during this iter)
            if (i + 1 < 128) stage_Ct32(Ctb, CtB + (cur ^ 1) * 16384, (i + 1) * 32, w4, lane);
            // ---- QK(i): 16n x 32m per wave (r19 2-chain form) ----
            f32x4 S0 = (f32x4)(0.f), S1 = (f32x4)(0.f);
            const f16* cb = CtB + cur * 16384;
            __builtin_amdgcn_s_setprio(1);
            #pragma unroll
            for (int s = 0; s < 16; ++s) {
                int ch = s * 4 + g;
                f16x8 b0 = *(const f16x8*)(cb + l15 * 512 + ((ch ^ (l15 & 7)) << 3));
                f16x8 b1 = *(const f16x8*)(cb + (16 + l15) * 512 + ((ch ^ (l15 & 7)) << 3));
                f16x8 q = __builtin_bit_cast(f16x8, R[s]);
                S0 = MFMA16(q, b0, S0);
                S1 = MFMA16(q, b1, S1);
            }
            __builtin_amdgcn_s_setprio(0);
            // ---- wave-local softmax (exp2 domain) with T13 defer-rescale ----
            f32x4 tm, scl;
            #pragma unroll
            for (int q = 0; q < 4; ++q) tm[q] = fmaxf(S0[q], S1[q]);
            tm = rmax16(tm);
            int grow = 0;
            #pragma unroll
            for (int q = 0; q < 4; ++q) grow |= (tm[q] > m_run[q] + THR2) ? 1 : 0;
            const bool doR = __any(grow);
            if (doR) {
                #pragma unroll
                for (int q = 0; q < 4; ++q) {
                    float mnew = fmaxf(m_run[q], tm[q]);
                    scl[q] = exp2f(m_run[q] - mnew);
                    m_run[q] = mnew;
                }
            } else {
                #pragma unroll
                for (int q = 0; q < 4; ++q) scl[q] = 1.0f;
            }
            #pragma unroll
            for (int q = 0; q < 4; ++q) {
                S0[q] = exp2f(S0[q] - m_run[q]);
                S1[q] = exp2f(S1[q] - m_run[q]);
            }
            f32x4 ps;
            #pragma unroll
            for (int q = 0; q < 4; ++q) ps[q] = S0[q] + S1[q];
            ps = rsum16(ps);
            #pragma unroll
            for (int q = 0; q < 4; ++q) l_run[q] = l_run[q] * scl[q] + ps[q];
            if (l15 == 0) *(f32x4*)(SCL + cur * 64 + w4 * 16 + g * 4) = scl;
            if (lane == 0) FLG[cur * 4 + w4] = doR ? 1 : 0;
            // P write, chunk-swizzled, padded stride
            f16* pp = PSB + cur * PBUF;
            #pragma unroll
            for (int q = 0; q < 4; ++q) {
                int row = w4 * 16 + g * 4 + q;
                pp[row * PSTRIDE + ((((l15 >> 3) ^ g) << 3) | (l15 & 7))] = (f16)S0[q];
                pp[row * PSTRIDE + ((((2 + (l15 >> 3)) ^ g) << 3) | (l15 & 7))] = (f16)S1[q];
            }
        } else {
            if (i > 0) {
                // ---- PV(i-1): 64n x 128c per wave ----
                const int prev = cur ^ 1;
                const f16* pp = PSB + prev * PBUF;
                const int fl = FLG[prev * 4 + 0] | FLG[prev * 4 + 1] |
                               FLG[prev * 4 + 2] | FLG[prev * 4 + 3];
                if (fl) {                      // wave-uniform branch
                    const float* sc = SCL + prev * 64;
                    f32x4 scl4[4];
                    #pragma unroll
                    for (int na = 0; na < 4; ++na)
                        scl4[na] = *(const f32x4*)(sc + na * 16 + g * 4);
                    #pragma unroll
                    for (int na = 0; na < 4; ++na)
                        #pragma unroll
                        for (int cb = 0; cb < 8; ++cb)
                            #pragma unroll
                            for (int q = 0; q < 4; ++q)
                                R[na * 8 + cb][q] *= scl4[na][q];
                }
                f16x8 pa[4];
                #pragma unroll
                for (int na = 0; na < 4; ++na) {
                    int row = na * 16 + l15;
                    pa[na] = *(const f16x8*)(pp + row * PSTRIDE + ((g ^ (l15 >> 2)) << 3));
                }
                f16x8 d[8];
                #pragma unroll
                for (int cb = 0; cb < 8; ++cb)
                    d[cb] = *(const f16x8*)(DtB + (w4 * 128 + cb * 16 + l15) * 32 + dq);
                __builtin_amdgcn_s_setprio(1);
                #pragma unroll
                for (int na = 0; na < 4; ++na)
                    #pragma unroll
                    for (int cb = 0; cb < 8; ++cb)
                        R[na * 8 + cb] = MFMA16(pa[na], d[cb], R[na * 8 + cb]);
                __builtin_amdgcn_s_setprio(0);
                __builtin_amdgcn_sched_barrier(0);   // keep Dt restage below the reads
            }
            // restage own rows with Dt(i) (consumed at iter i+1)
            stage_Dt32(Dmb, DtB, i * 32, w4, lane);
        }
        __syncthreads();
    }

    // ---- epilogue E1: consumer does PV(127); producer publishes l ----
    if (isP) {
        if (l15 == 0) *(f32x4*)(LROW + w4 * 16 + g * 4) = l_run;
    } else {
        const f16* pp = PSB + PBUF;            // prev = 127&1 = 1
        const int fl = FLG[4 + 0] | FLG[4 + 1] | FLG[4 + 2] | FLG[4 + 3];
        if (fl) {
            const float* sc = SCL + 64;
            f32x4 scl4[4];
            #pragma unroll
            for (int na = 0; na < 4; ++na)
                scl4[na] = *(const f32x4*)(sc + na * 16 + g * 4);
            #pragma unroll
            for (int na = 0; na < 4; ++na)
                #pragma unroll
                for (int cb = 0; cb < 8; ++cb)
                    #pragma unroll
                    for (int q = 0; q < 4; ++q)
                        R[na * 8 + cb][q] *= scl4[na][q];
        }
        f16x8 pa[4];
        #pragma unroll
        for (int na = 0; na < 4; ++na) {
            int row = na * 16 + l15;
            pa[na] = *(const f16x8*)(pp + row * PSTRIDE + ((g ^ (l15 >> 2)) << 3));
        }
        f16x8 d[8];
        #pragma unroll
        for (int cb = 0; cb < 8; ++cb)
            d[cb] = *(const f16x8*)(DtB + (w4 * 128 + cb * 16 + l15) * 32 + dq);
        #pragma unroll
        for (int na = 0; na < 4; ++na)
            #pragma unroll
            for (int cb = 0; cb < 8; ++cb)
                R[na * 8 + cb] = MFMA16(pa[na], d[cb], R[na * 8 + cb]);
    }
    __syncthreads();

    // ---- E2: consumer writes T[c][n] = gamma * O / l ----
    const float gam = gamma_p[0];
    float* T = (float*)sm;                     // [512][68] f32 (LROW lives beyond)
    if (!isP) {
        #pragma unroll
        for (int na = 0; na < 4; ++na) {
            f32x4 lr = *(const f32x4*)(LROW + na * 16 + g * 4);
            f32x4 inv;
            #pragma unroll
            for (int q = 0; q < 4; ++q) inv[q] = gam / lr[q];
            #pragma unroll
            for (int cb = 0; cb < 8; ++cb) {
                int c = w4 * 128 + cb * 16 + l15;
                f32x4 v;
                #pragma unroll
                for (int q = 0; q < 4; ++q) v[q] = R[na * 8 + cb][q] * inv[q];
                *(f32x4*)(T + c * 68 + na * 16 + g * 4) = v;
            }
        }
    }
    __syncthreads();

    // ---- E3: all threads: out[c][n] = T + x ----
    const float* __restrict__ xb = x + (size_t)b * CC * NN;
    float* __restrict__ ob = out + (size_t)b * CC * NN;
    #pragma unroll
    for (int it = 0; it < 16; ++it) {
        int c = (t >> 4) + it * 32;
        int n4 = (t & 15) * 4;
        f32x4 v = *(const f32x4*)(T + c * 68 + n4);
        f32x4 xv = *(const f32x4*)(xb + (size_t)c * NN + n0 + n4);
        #pragma unroll
        for (int q = 0; q < 4; ++q) v[q] += xv[q];
        *(f32x4*)(ob + (size_t)c * NN + n0 + n4) = v;
    }
}

extern "C" void kernel_launch(void* const* d_in, const int* in_sizes, int n_in,
                              void* d_out, int out_size, void* d_ws, size_t ws_size,
                              hipStream_t stream) {
    const float* x  = (const float*)d_in[0];
    const float* Wb = (const float*)d_in[1];
    const float* Wc = (const float*)d_in[2];
    const float* Wd = (const float*)d_in[3];
    const float* gm = (const float*)d_in[4];
    float* out = (float*)d_out;
    char* ws = (char*)d_ws;

    // ws: W16 1.5MB | Bt 16MB | Ct 16MB | Dm 16MB | Xt 16MB  (~66MB)
    f16* W16 = (f16*)(ws);
    f16* Bt  = (f16*)(ws + 1572864);
    f16* Ct  = (f16*)(ws + 1572864 + 16777216);
    f16* Dm  = (f16*)(ws + 1572864 + 2 * 16777216);
    f16* Xt  = (f16*)(ws + 1572864 + 3 * 16777216);

    wcvt_k<<<dim3(768), 256, 0, stream>>>(Wb, Wc, Wd, W16);
    xt_k<<<dim3(NN / 64, CC / 64, BB), 256, 0, stream>>>(x, Xt);
    proj_k<<<dim3(32, 4, 12), 256, 0, stream>>>(Xt, W16, Bt, Ct, Dm);
    flash_k<<<dim3(256), 512, 0, stream>>>(x, gm, Bt, Ct, Dm, out);
}

// Round 23
// 326.080 us; speedup vs baseline: 1.0749x; 1.0127x over previous
//
#include <hip/hip_runtime.h>
#include <math.h>
#include <stdint.h>

#define CC 512
#define NN 4096
#define BB 4

typedef _Float16 f16;
typedef _Float16 f16x8 __attribute__((ext_vector_type(8)));
typedef _Float16 f16x4 __attribute__((ext_vector_type(4)));
typedef float f32x4 __attribute__((ext_vector_type(4)));

// ---------- async global->LDS 16B ----------
__device__ __forceinline__ void gload_lds16(const void* g, void* l) {
    __builtin_amdgcn_global_load_lds(
        (const __attribute__((address_space(1))) void*)g,
        (__attribute__((address_space(3))) void*)l, 16, 0, 0);
}

// Stage ROWS rows x 64 f16 from K-major global into linear LDS; source pre-swizzled.
template<int ROWS>
__device__ __forceinline__ void stage_tile(const f16* __restrict__ g, int stride_e,
                                           f16* lds, int wid, int lane) {
    constexpr int ITERS = ROWS * 8 / 64 / 4;   // 4 waves
    #pragma unroll
    for (int it = 0; it < ITERS; ++it) {
        int flatbase = (wid * ITERS + it) * 64;
        f16* dst = lds + flatbase * 8;
        int flat = flatbase + lane;
        int r = flat >> 3, c = flat & 7;
        const f16* src = g + (size_t)r * stride_e + ((c ^ (r & 7)) << 3);
        gload_lds16(src, dst);
    }
}

__device__ __forceinline__ f16x8 frag_ld(const f16* lds, int r, int ch) {
    return *(const f16x8*)(lds + r * 64 + ((ch ^ (r & 7)) << 3));
}

#define MFMA16(a, b, c) __builtin_amdgcn_mfma_f32_16x16x32_f16((a), (b), (c), 0, 0, 0)

// ---------- DPP row_ror reductions over 16-lane rows (VALU only) ----------
template<int N>
__device__ __forceinline__ float ror16(float x) {
    return __int_as_float(__builtin_amdgcn_update_dpp(
        0, __float_as_int(x), 0x120 + N, 0xF, 0xF, true));
}
__device__ __forceinline__ f32x4 rmax16(f32x4 v) {
    #pragma unroll
    for (int q = 0; q < 4; ++q) {
        float x = v[q];
        x = fmaxf(x, ror16<1>(x));
        x = fmaxf(x, ror16<2>(x));
        x = fmaxf(x, ror16<4>(x));
        x = fmaxf(x, ror16<8>(x));
        v[q] = x;
    }
    return v;
}
__device__ __forceinline__ f32x4 rsum16(f32x4 v) {
    #pragma unroll
    for (int q = 0; q < 4; ++q) {
        float x = v[q];
        x += ror16<1>(x);
        x += ror16<2>(x);
        x += ror16<4>(x);
        x += ror16<8>(x);
        v[q] = x;
    }
    return v;
}

// ---------------- prep: W conversion + x transpose-convert (merged, one launch) ----------------
// blocks 0..767: W16 = f16(W{b,c,d})  (768 blocks)
// blocks 768..2815: Xt[b][n][c] = f16(x[b][c][n])  (2048 blocks = 64 x 8 x 4)
__global__ __launch_bounds__(256) void prep_k(const float* __restrict__ x,
                                              const float* __restrict__ Wb,
                                              const float* __restrict__ Wc,
                                              const float* __restrict__ Wd,
                                              f16* __restrict__ W16,
                                              f16* __restrict__ Xt) {
    __shared__ float T[64][65];
    const int lin = blockIdx.x;
    const int t = threadIdx.x;
    if (lin < 768) {
        int i = lin * 256 + t;
        int idx = i * 4;
        int m = idx >> 18;
        int off = idx & 262143;
        const float* src = (m == 0) ? Wb : (m == 1) ? Wc : Wd;
        f32x4 v = *(const f32x4*)(src + off);
        f16x4 h = { (f16)v[0], (f16)v[1], (f16)v[2], (f16)v[3] };
        *(f16x4*)(W16 + idx) = h;
        return;
    }
    const int e = lin - 768;
    const int b = e >> 9;                      // / 512
    const int rem = e & 511;
    const int c0 = (rem >> 6) * 64;            // 8 c-tiles
    const int n0 = (rem & 63) * 64;            // 64 n-tiles
    const float* __restrict__ xb = x + (size_t)b * CC * NN;
    const int cl = t >> 4, n4 = (t & 15) * 4;
    #pragma unroll
    for (int it = 0; it < 4; ++it) {
        f32x4 v = *(const f32x4*)(xb + (size_t)(c0 + cl + it * 16) * NN + n0 + n4);
        T[cl + it * 16][n4 + 0] = v[0];
        T[cl + it * 16][n4 + 1] = v[1];
        T[cl + it * 16][n4 + 2] = v[2];
        T[cl + it * 16][n4 + 3] = v[3];
    }
    __syncthreads();
    f16* __restrict__ xtb = Xt + (size_t)b * NN * CC;
    const int nl = t >> 2, seg = (t & 3) * 16;
    f16 tmp[16];
    #pragma unroll
    for (int j = 0; j < 16; ++j) tmp[j] = (f16)T[seg + j][nl];
    *(f16x8*)(xtb + (size_t)(n0 + nl) * CC + c0 + seg)     = *(f16x8*)(tmp);
    *(f16x8*)(xtb + (size_t)(n0 + nl) * CC + c0 + seg + 8) = *(f16x8*)(tmp + 8);
}

// ---------------- proj (all batches): O = W @ x, both operands f16 K-major ----------------
// Bt (wsel==0) is pre-scaled by log2(e): flash runs softmax in exp2 domain.
__global__ __launch_bounds__(256) void proj_k(const f16* __restrict__ Xt,
                                              const f16* __restrict__ W16,
                                              f16* __restrict__ Bt, f16* __restrict__ Ct,
                                              f16* __restrict__ Dm) {
    const int wsel = blockIdx.z % 3;
    const int b = blockIdx.z / 3;
    const f16* __restrict__ W = W16 + (size_t)wsel * CC * CC;
    const f16* __restrict__ XtB = Xt + (size_t)b * NN * CC;   // [n][c]
    const size_t p16 = (size_t)CC * NN;
    const int o0 = blockIdx.y * 128, n0 = blockIdx.x * 128;

    __shared__ __align__(16) char smraw[34816];
    f16* As = (f16*)smraw;
    f16* Bs = As + 128 * 64;
    f16* T  = (f16*)smraw;

    const int t = threadIdx.x;
    const int wid = t >> 6, lane = t & 63;
    const int wr = wid >> 1, wc = wid & 1;

    f32x4 acc[4][4] = {};

    for (int kc = 0; kc < CC; kc += 64) {
        __syncthreads();
        stage_tile<128>(W + (size_t)o0 * CC + kc, CC, As, wid, lane);
        stage_tile<128>(XtB + (size_t)n0 * CC + kc, CC, Bs, wid, lane);
        __syncthreads();
        #pragma unroll
        for (int ks = 0; ks < 2; ++ks) {
            int ch = ks * 4 + (lane >> 4);
            f16x8 a[4], bb[4];
            #pragma unroll
            for (int i = 0; i < 4; ++i) a[i]  = frag_ld(As, wr * 64 + i * 16 + (lane & 15), ch);
            #pragma unroll
            for (int j = 0; j < 4; ++j) bb[j] = frag_ld(Bs, wc * 64 + j * 16 + (lane & 15), ch);
            #pragma unroll
            for (int i = 0; i < 4; ++i)
                #pragma unroll
                for (int j = 0; j < 4; ++j)
                    acc[i][j] = MFMA16(a[i], bb[j], acc[i][j]);
        }
    }

    __syncthreads();
    const float osc = (wsel == 0) ? 1.4426950408889634f : 1.0f;   // log2(e) for Bt only
    if (wsel < 2) {
        #pragma unroll
        for (int i = 0; i < 4; ++i)
            #pragma unroll
            for (int j = 0; j < 4; ++j) {
                int n_l = wc * 64 + j * 16 + (lane & 15);
                int o_l = wr * 64 + i * 16 + (lane >> 4) * 4;
                f16x4 h = { (f16)(acc[i][j][0] * osc), (f16)(acc[i][j][1] * osc),
                            (f16)(acc[i][j][2] * osc), (f16)(acc[i][j][3] * osc) };
                *(f16x4*)(T + n_l * 136 + o_l) = h;
            }
        __syncthreads();
        f16* __restrict__ dst = ((wsel == 0) ? Bt : Ct) + (size_t)b * p16;
        int n = t & 127;
        #pragma unroll
        for (int it = 0; it < 8; ++it) {
            int ch8 = (t >> 7) * 8 + it;
            f16x8 h = *(f16x8*)(T + n * 136 + ch8 * 8);
            *(f16x8*)(dst + (size_t)(n0 + n) * CC + o0 + ch8 * 8) = h;
        }
    } else {
        #pragma unroll
        for (int i = 0; i < 4; ++i)
            #pragma unroll
            for (int j = 0; j < 4; ++j) {
                int n_l = wc * 64 + j * 16 + (lane & 15);
                #pragma unroll
                for (int q = 0; q < 4; ++q) {
                    int o_l = wr * 64 + i * 16 + (lane >> 4) * 4 + q;
                    T[o_l * 136 + n_l] = (f16)acc[i][j][q];
                }
            }
        __syncthreads();
        f16* __restrict__ dst = Dm + (size_t)b * p16;
        int o = t & 127;
        #pragma unroll
        for (int it = 0; it < 8; ++it) {
            int ch8 = (t >> 7) * 8 + it;
            f16x8 h = *(f16x8*)(T + o * 136 + ch8 * 8);
            *(f16x8*)(dst + (size_t)(o0 + o) * NN + n0 + ch8 * 8) = h;
        }
    }
}

// ---------- flash staging (32-m tiles) ----------
__device__ __forceinline__ void stage_Ct32(const f16* __restrict__ Ctb, f16* dstbase,
                                           int m0, int w4, int lane) {
    #pragma unroll
    for (int it = 0; it < 8; ++it) {
        int flatbase = (w4 * 8 + it) * 64;
        f16* dst = dstbase + flatbase * 8;
        int r = flatbase >> 6;                // uniform: w4*8+it
        const f16* src = Ctb + (size_t)(m0 + r) * CC + ((lane ^ (r & 7)) << 3);
        gload_lds16(src, dst);
    }
}
// DtB tile [512 c][32 m], rows 64B apart, both-sides quarter swizzle (r19, proven).
__device__ __forceinline__ void stage_Dt32(const f16* __restrict__ Dmb, f16* DtB,
                                           int m0, int w4, int lane) {
    #pragma unroll
    for (int it = 0; it < 8; ++it) {
        int flatbase = (w4 * 8 + it) * 64;
        f16* dst = DtB + flatbase * 8;
        int flat = flatbase + lane;
        int r = flat >> 2, c4 = flat & 3;
        const f16* src = Dmb + (size_t)r * NN + m0 + (((c4 ^ ((r >> 1) & 3))) << 3);
        gload_lds16(src, dst);
    }
}

#define PSTRIDE 40
#define PBUF    2560   // 64 * PSTRIDE
#define THR2    11.5415603f   // 8 nats in bits

// ---------------- fused flash attention (r21 proven: 291us, zero spill) ----------------
// Waves 0-3: QK^T (2-chain) + wave-local softmax (exp2 domain) + T13 defer-rescale.
// Waves 4-7: PV(i-1), O = 64n x 128c; restage Dt after PV. ONE __syncthreads/iter.
// NOTE: SCL store is UNCONDITIONAL (writes 1.0 when !doR). r22's conditional store
// raced: consumers gate on OR of all 4 flags, so when producer waves disagreed the
// doR=0 producer's rows got a STALE scale from 2 tiles prior (absmax 0.5 fail).
__global__ __launch_bounds__(512) void flash_k(
    const float* __restrict__ x, const float* __restrict__ gamma_p,
    const f16* __restrict__ Bt, const f16* __restrict__ Ct,
    const f16* __restrict__ Dm, float* __restrict__ out)
{
    __shared__ __align__(16) char sm[139776];
    f16*   CtB  = (f16*)sm;                    // [2][32][512]  65536 B
    f16*   DtB  = (f16*)(sm + 65536);          // [512][32]     32768 B (quarter-swizzled)
    f16*   PSB  = (f16*)(sm + 98304);          // [2][64][40]   10240 B (padded stride)
    float* SCL  = (float*)(sm + 108544);       // [2][64]         512 B
    int*   FLG  = (int*)(sm + 109056);         // [2][4]           32 B
    float* LROW = (float*)(sm + 139264);       // [64]            256 B (beyond T)
    // epilogue: T = (float*)sm, [512][68] f32 = 139264 B

    // XCD-pair swizzle: 256 blocks
    const int bx = blockIdx.x;
    const int j8 = bx & 7;
    const int b = j8 >> 1;
    const int n0 = ((bx >> 3) + (j8 & 1) * 32) * 64;

    const size_t p16 = (size_t)CC * NN;
    const f16* __restrict__ Btb = Bt + (size_t)b * p16;   // [n][c] (log2e-scaled)
    const f16* __restrict__ Ctb = Ct + (size_t)b * p16;   // [m][c]
    const f16* __restrict__ Dmb = Dm + (size_t)b * p16;   // [c][m]

    const int t = threadIdx.x;
    const int wid = t >> 6, lane = t & 63;
    const int w4 = wid & 3;
    const bool isP = wid < 4;                  // producer gang
    const int l15 = lane & 15, g = lane >> 4;
    const int dq = (g ^ ((l15 >> 1) & 3)) << 3;

    f32x4 R[32];                               // producer: R[0..15] = Q; consumer: O[4][8]
    f32x4 m_run = (f32x4)(-INFINITY);
    f32x4 l_run = (f32x4)(0.f);

    if (isP) {
        const f16* qrow = Btb + (size_t)(n0 + w4 * 16 + l15) * CC + g * 8;
        #pragma unroll
        for (int s = 0; s < 16; ++s)
            R[s] = __builtin_bit_cast(f32x4, *(const f16x8*)(qrow + s * 32));
    } else {
        #pragma unroll
        for (int i = 0; i < 32; ++i) R[i] = (f32x4)(0.f);
    }

    if (isP) stage_Ct32(Ctb, CtB, 0, w4, lane);
    __syncthreads();

    for (int i = 0; i < 128; ++i) {
        const int cur = i & 1;
        if (isP) {
            if (i + 1 < 128) stage_Ct32(Ctb, CtB + (cur ^ 1) * 16384, (i + 1) * 32, w4, lane);
            // ---- QK(i): 16n x 32m per wave ----
            f32x4 S0 = (f32x4)(0.f), S1 = (f32x4)(0.f);
            const f16* cb = CtB + cur * 16384;
            __builtin_amdgcn_s_setprio(1);
            #pragma unroll
            for (int s = 0; s < 16; ++s) {
                int ch = s * 4 + g;
                f16x8 b0 = *(const f16x8*)(cb + l15 * 512 + ((ch ^ (l15 & 7)) << 3));
                f16x8 b1 = *(const f16x8*)(cb + (16 + l15) * 512 + ((ch ^ (l15 & 7)) << 3));
                f16x8 q = __builtin_bit_cast(f16x8, R[s]);
                S0 = MFMA16(q, b0, S0);
                S1 = MFMA16(q, b1, S1);
            }
            __builtin_amdgcn_s_setprio(0);
            // ---- wave-local softmax (exp2 domain) with T13 defer-rescale ----
            f32x4 tm, scl;
            #pragma unroll
            for (int q = 0; q < 4; ++q) tm[q] = fmaxf(S0[q], S1[q]);
            tm = rmax16(tm);
            int grow = 0;
            #pragma unroll
            for (int q = 0; q < 4; ++q) grow |= (tm[q] > m_run[q] + THR2) ? 1 : 0;
            const bool doR = __any(grow);
            if (doR) {
                #pragma unroll
                for (int q = 0; q < 4; ++q) {
                    float mnew = fmaxf(m_run[q], tm[q]);
                    scl[q] = exp2f(m_run[q] - mnew);
                    m_run[q] = mnew;
                }
            } else {
                #pragma unroll
                for (int q = 0; q < 4; ++q) scl[q] = 1.0f;
            }
            #pragma unroll
            for (int q = 0; q < 4; ++q) {
                S0[q] = exp2f(S0[q] - m_run[q]);
                S1[q] = exp2f(S1[q] - m_run[q]);
            }
            f32x4 ps;
            #pragma unroll
            for (int q = 0; q < 4; ++q) ps[q] = S0[q] + S1[q];
            ps = rsum16(ps);
            #pragma unroll
            for (int q = 0; q < 4; ++q) l_run[q] = l_run[q] * scl[q] + ps[q];
            if (l15 == 0) *(f32x4*)(SCL + cur * 64 + w4 * 16 + g * 4) = scl;   // UNCONDITIONAL
            if (lane == 0) FLG[cur * 4 + w4] = doR ? 1 : 0;
            // P write, chunk-swizzled, padded stride
            f16* pp = PSB + cur * PBUF;
            #pragma unroll
            for (int q = 0; q < 4; ++q) {
                int row = w4 * 16 + g * 4 + q;
                pp[row * PSTRIDE + ((((l15 >> 3) ^ g) << 3) | (l15 & 7))] = (f16)S0[q];
                pp[row * PSTRIDE + ((((2 + (l15 >> 3)) ^ g) << 3) | (l15 & 7))] = (f16)S1[q];
            }
        } else {
            if (i > 0) {
                // ---- PV(i-1): 64n x 128c per wave ----
                const int prev = cur ^ 1;
                const f16* pp = PSB + prev * PBUF;
                const int fl = FLG[prev * 4 + 0] | FLG[prev * 4 + 1] |
                               FLG[prev * 4 + 2] | FLG[prev * 4 + 3];
                if (fl) {                      // wave-uniform branch
                    const float* sc = SCL + prev * 64;
                    f32x4 scl4[4];
                    #pragma unroll
                    for (int na = 0; na < 4; ++na)
                        scl4[na] = *(const f32x4*)(sc + na * 16 + g * 4);
                    #pragma unroll
                    for (int na = 0; na < 4; ++na)
                        #pragma unroll
                        for (int cb = 0; cb < 8; ++cb)
                            #pragma unroll
                            for (int q = 0; q < 4; ++q)
                                R[na * 8 + cb][q] *= scl4[na][q];
                }
                f16x8 pa[4];
                #pragma unroll
                for (int na = 0; na < 4; ++na) {
                    int row = na * 16 + l15;
                    pa[na] = *(const f16x8*)(pp + row * PSTRIDE + ((g ^ (l15 >> 2)) << 3));
                }
                f16x8 d[8];
                #pragma unroll
                for (int cb = 0; cb < 8; ++cb)
                    d[cb] = *(const f16x8*)(DtB + (w4 * 128 + cb * 16 + l15) * 32 + dq);
                __builtin_amdgcn_s_setprio(1);
                #pragma unroll
                for (int na = 0; na < 4; ++na)
                    #pragma unroll
                    for (int cb = 0; cb < 8; ++cb)
                        R[na * 8 + cb] = MFMA16(pa[na], d[cb], R[na * 8 + cb]);
                __builtin_amdgcn_s_setprio(0);
                __builtin_amdgcn_sched_barrier(0);   // keep Dt restage below the reads
            }
            // restage own rows with Dt(i) (consumed at iter i+1)
            stage_Dt32(Dmb, DtB, i * 32, w4, lane);
        }
        __syncthreads();
    }

    // ---- epilogue E1: consumer does PV(127); producer publishes l ----
    if (isP) {
        if (l15 == 0) *(f32x4*)(LROW + w4 * 16 + g * 4) = l_run;
    } else {
        const f16* pp = PSB + PBUF;            // prev = 127&1 = 1
        const int fl = FLG[4 + 0] | FLG[4 + 1] | FLG[4 + 2] | FLG[4 + 3];
        if (fl) {
            const float* sc = SCL + 64;
            f32x4 scl4[4];
            #pragma unroll
            for (int na = 0; na < 4; ++na)
                scl4[na] = *(const f32x4*)(sc + na * 16 + g * 4);
            #pragma unroll
            for (int na = 0; na < 4; ++na)
                #pragma unroll
                for (int cb = 0; cb < 8; ++cb)
                    #pragma unroll
                    for (int q = 0; q < 4; ++q)
                        R[na * 8 + cb][q] *= scl4[na][q];
        }
        f16x8 pa[4];
        #pragma unroll
        for (int na = 0; na < 4; ++na) {
            int row = na * 16 + l15;
            pa[na] = *(const f16x8*)(pp + row * PSTRIDE + ((g ^ (l15 >> 2)) << 3));
        }
        f16x8 d[8];
        #pragma unroll
        for (int cb = 0; cb < 8; ++cb)
            d[cb] = *(const f16x8*)(DtB + (w4 * 128 + cb * 16 + l15) * 32 + dq);
        #pragma unroll
        for (int na = 0; na < 4; ++na)
            #pragma unroll
            for (int cb = 0; cb < 8; ++cb)
                R[na * 8 + cb] = MFMA16(pa[na], d[cb], R[na * 8 + cb]);
    }
    __syncthreads();

    // ---- E2: consumer writes T[c][n] = gamma * O / l ----
    const float gam = gamma_p[0];
    float* T = (float*)sm;                     // [512][68] f32 (LROW lives beyond)
    if (!isP) {
        #pragma unroll
        for (int na = 0; na < 4; ++na) {
            f32x4 lr = *(const f32x4*)(LROW + na * 16 + g * 4);
            f32x4 inv;
            #pragma unroll
            for (int q = 0; q < 4; ++q) inv[q] = gam / lr[q];
            #pragma unroll
            for (int cb = 0; cb < 8; ++cb) {
                int c = w4 * 128 + cb * 16 + l15;
                f32x4 v;
                #pragma unroll
                for (int q = 0; q < 4; ++q) v[q] = R[na * 8 + cb][q] * inv[q];
                *(f32x4*)(T + c * 68 + na * 16 + g * 4) = v;
            }
        }
    }
    __syncthreads();

    // ---- E3: all threads: out[c][n] = T + x ----
    const float* __restrict__ xb = x + (size_t)b * CC * NN;
    float* __restrict__ ob = out + (size_t)b * CC * NN;
    #pragma unroll
    for (int it = 0; it < 16; ++it) {
        int c = (t >> 4) + it * 32;
        int n4 = (t & 15) * 4;
        f32x4 v = *(const f32x4*)(T + c * 68 + n4);
        f32x4 xv = *(const f32x4*)(xb + (size_t)c * NN + n0 + n4);
        #pragma unroll
        for (int q = 0; q < 4; ++q) v[q] += xv[q];
        *(f32x4*)(ob + (size_t)c * NN + n0 + n4) = v;
    }
}

extern "C" void kernel_launch(void* const* d_in, const int* in_sizes, int n_in,
                              void* d_out, int out_size, void* d_ws, size_t ws_size,
                              hipStream_t stream) {
    const float* x  = (const float*)d_in[0];
    const float* Wb = (const float*)d_in[1];
    const float* Wc = (const float*)d_in[2];
    const float* Wd = (const float*)d_in[3];
    const float* gm = (const float*)d_in[4];
    float* out = (float*)d_out;
    char* ws = (char*)d_ws;

    // ws: W16 1.5MB | Bt 16MB | Ct 16MB | Dm 16MB | Xt 16MB  (~66MB)
    f16* W16 = (f16*)(ws);
    f16* Bt  = (f16*)(ws + 1572864);
    f16* Ct  = (f16*)(ws + 1572864 + 16777216);
    f16* Dm  = (f16*)(ws + 1572864 + 2 * 16777216);
    f16* Xt  = (f16*)(ws + 1572864 + 3 * 16777216);

    prep_k<<<dim3(768 + 2048), 256, 0, stream>>>(x, Wb, Wc, Wd, W16, Xt);
    proj_k<<<dim3(32, 4, 12), 256, 0, stream>>>(Xt, W16, Bt, Ct, Dm);
    flash_k<<<dim3(256), 512, 0, stream>>>(x, gm, Bt, Ct, Dm, out);
}